// Round 1
// baseline (78.056 us; speedup 1.0000x reference)
//
#include <hip/hip_runtime.h>
#include <math.h>

#define SIDELEN 128
#define KCOEF   5
#define TILE    8      // 8x8 pixel tile per block
#define TPB     256    // 4 waves; atom list split across the 4 waves

__device__ __forceinline__ float fexp2(float x) { return __builtin_amdgcn_exp2f(x); }
__device__ __forceinline__ float frcp(float x)  { return __builtin_amdgcn_rcpf(x); }

// Tiled GATHER (replaces atomic scatter). One block = one 8x8 output tile;
// lane l of every wave owns pixel (tr + (l>>3), tc + (l&7)). The 4 waves
// partition the atom list; each wave scans 64-atom coalesced chunks,
// ballots membership against the tile's +-4.5px halo box, then broadcasts
// each member atom's (u, v, c2[k], w[k]) via __shfl and accumulates.
//
// Membership box [tr-4.5, tr+7+4.5] x [tc-4.5, tc+7+4.5] is a strict
// superset of the old scatter's 8x8 patch footprint (dx in [-4,4]), so the
// truncation error is <= the previously-passing kernel's (excluded pairs
// have d2 > 20.25 -> exp term < 3e-12).
//
// Every output pixel is fully overwritten (no reliance on poison ~= 0,
// no atomics, coalesced stores).
__global__ __launch_bounds__(256) void potential_gather8(
    const float* __restrict__ coords,   // (B, A, 3)
    const float* __restrict__ ffa,      // (A, K)
    const float* __restrict__ ffb,      // (A, K)
    float* __restrict__ out,            // (B, 128, 128) fp32
    int B, int A)
{
    const int tid  = threadIdx.x;
    const int wid  = tid >> 6;
    const int lane = tid & 63;

    const int blk  = blockIdx.x;
    const int b    = blk >> 8;          // 256 tiles per batch image
    const int tile = blk & 255;
    const int tr   = (tile >> 4) * TILE;
    const int tc   = (tile & 15) * TILE;

    const float prf = (float)(tr + (lane >> 3));   // this lane's pixel row
    const float pcf = (float)(tc + (lane & 7));    // this lane's pixel col

    const float rlo = (float)tr - 4.5f;
    const float rhi = (float)tr + (float)(TILE - 1) + 4.5f;
    const float clo = (float)tc - 4.5f;
    const float chi = (float)tc + (float)(TILE - 1) + 4.5f;

    const float* cb = coords + (size_t)b * A * 3;

    float acc = 0.0f;

    for (int base = wid * 64; base < A; base += TPB) {
        const int ai = base + lane;

        // coalesced-ish chunk load of this wave's 64 atoms (stride-3 floats)
        float u = -1.0e30f, v = -1.0e30f;
        if (ai < A) {
            u = cb[(size_t)ai * 3 + 0] + 64.0f;   // row (X) axis, pixel space
            v = cb[(size_t)ai * 3 + 1] + 64.0f;   // col (Y) axis
        }

        const bool member = (u >= rlo) & (u <= rhi) & (v >= clo) & (v <= chi);

        // per-atom coefficients, only fetched for members (exec-masked loads)
        float c2[KCOEF], w[KCOEF];
        if (member) {
#pragma unroll
            for (int k = 0; k < KCOEF; ++k) {
                const float af = ffa[ai * KCOEF + k];
                const float bf = ffb[ai * KCOEF + k];
                const float rb = frcp(bf);
                c2[k] = -56.95531725f * rb;     // -4*pi^2*log2(e)/b
                w[k]  = 12.56637061f * af * rb; //  4*pi*a/b
            }
        }

        unsigned long long m = __ballot(member);
        while (m) {
            const int j = __builtin_ctzll(m);
            m &= m - 1;

            const float au = __shfl(u, j);
            const float av = __shfl(v, j);
            const float dx = prf - au;
            const float dy = pcf - av;
            const float d2 = fmaf(dx, dx, dy * dy);
#pragma unroll
            for (int k = 0; k < KCOEF; ++k) {
                const float cc = __shfl(c2[k], j);
                const float ww = __shfl(w[k],  j);
                acc = fmaf(ww, fexp2(cc * d2), acc);
            }
        }
    }

    // cross-wave reduction: same 64 pixels in every wave
    __shared__ float sm[4][64];
    sm[wid][lane] = acc;
    __syncthreads();
    if (wid == 0) {
        const float val = sm[0][lane] + sm[1][lane] + sm[2][lane] + sm[3][lane];
        const int r = tr + (lane >> 3);
        const int c = tc + (lane & 7);
        out[((size_t)b << 14) + r * SIDELEN + c] = val;
    }
}

extern "C" void kernel_launch(void* const* d_in, const int* in_sizes, int n_in,
                              void* d_out, int out_size, void* d_ws, size_t ws_size,
                              hipStream_t stream) {
    const float* coords = (const float*)d_in[0];   // (B, A, 3)
    const float* ffa    = (const float*)d_in[1];   // (A, K)
    const float* ffb    = (const float*)d_in[2];   // (A, K)
    float* out = (float*)d_out;

    const int A = in_sizes[1] / KCOEF;
    const int B = in_sizes[0] / (3 * A);

    const int nblk = B * 256;                      // one block per 8x8 tile
    potential_gather8<<<dim3(nblk), dim3(TPB), 0, stream>>>(
        coords, ffa, ffb, out, B, A);
}

// Round 2
// 65.948 us; speedup vs baseline: 1.1836x; 1.1836x over previous
//
#include <hip/hip_runtime.h>
#include <math.h>

#define SIDELEN 128
#define KCOEF   5
#define TILE    8       // 8x8 pixel tile per block
#define NW      16      // waves per block
#define TPB     (NW*64) // 1024 threads

__device__ __forceinline__ float fexp2(float x) { return __builtin_amdgcn_exp2f(x); }
__device__ __forceinline__ float frcp(float x)  { return __builtin_amdgcn_rcpf(x); }

// Tiled gather, LDS-compaction variant. One block = one 8x8 output tile;
// lane l of every wave owns pixel (tr + (l>>3), tc + (l&7)). The 16 waves
// partition the atom list (2 chunks of 64 per wave at A=2048).
//
// Round-1 lesson: per-member __shfl broadcast = ~11 serialized ds_bpermute
// + lgkmcnt(0) waits (~1300 cy/member) -> 38 us critical block. Replaced by
// per-CHUNK compaction: member lanes write a 12-float record
// [u v c2_0 w_0 ... c2_4 w_4] into a wave-private compacted LDS list
// (slot = popc-prefix of ballot); then a uniform loop reads records via
// wave-uniform ds_read_b128 (broadcast, conflict-free, pipelinable).
// One LDS dependency per chunk instead of ~11 per member.
//
// Membership box (+-4.5 px halo) is a strict superset of the original
// scatter's 8x8 patch footprint -> truncation error <= the passing kernel's
// (excluded pairs have d2 > 20.25, exp term < 3e-12).
//
// Every output pixel fully overwritten; no atomics; coalesced stores.
__global__ __launch_bounds__(TPB) void potential_gather_lds(
    const float* __restrict__ coords,   // (B, A, 3)
    const float* __restrict__ ffa,      // (A, K)
    const float* __restrict__ ffb,      // (A, K)
    float* __restrict__ out,            // (B, 128, 128) fp32
    int B, int A)
{
    const int tid  = threadIdx.x;
    const int wid  = tid >> 6;
    const int lane = tid & 63;

    const int blk  = blockIdx.x;
    const int b    = blk >> 8;          // 256 tiles per batch image
    const int tile = blk & 255;
    const int tr   = (tile >> 4) * TILE;
    const int tc   = (tile & 15) * TILE;

    const float prf = (float)(tr + (lane >> 3));   // this lane's pixel row
    const float pcf = (float)(tc + (lane & 7));    // this lane's pixel col

    const float rlo = (float)tr - 4.5f;
    const float rhi = (float)tr + (float)(TILE - 1) + 4.5f;
    const float clo = (float)tc - 4.5f;
    const float chi = (float)tc + (float)(TILE - 1) + 4.5f;

    // wave-private compacted member records: 12 floats, 48B stride (16B-aligned)
    __shared__ __align__(16) float pool[NW][64][12];   // 48 KiB
    __shared__ float smred[NW][64];                    //  4 KiB

    const float* cb = coords + (size_t)b * A * 3;

    float acc = 0.0f;

    for (int base = wid * 64; base < A; base += TPB) {
        const int ai = base + lane;

        float u = -1.0e30f, v = -1.0e30f;
        if (ai < A) {
            u = cb[(size_t)ai * 3 + 0] + 64.0f;   // row (X) axis, pixel space
            v = cb[(size_t)ai * 3 + 1] + 64.0f;   // col (Y) axis
        }

        const bool member = (u >= rlo) & (u <= rhi) & (v >= clo) & (v <= chi);
        const unsigned long long m = __ballot(member);
        const int nm = __popcll(m);

        if (member) {
            const int pos = __popcll(m & ((1ull << lane) - 1ull));
            float cc[KCOEF], ww[KCOEF];
#pragma unroll
            for (int k = 0; k < KCOEF; ++k) {
                const float af = ffa[ai * KCOEF + k];
                const float bf = ffb[ai * KCOEF + k];
                const float rb = frcp(bf);
                cc[k] = -56.95531725f * rb;     // -4*pi^2*log2(e)/b
                ww[k] = 12.56637061f * af * rb; //  4*pi*a/b
            }
            float4* s = (float4*)&pool[wid][pos][0];
            s[0] = make_float4(u,     v,     cc[0], ww[0]);
            s[1] = make_float4(cc[1], ww[1], cc[2], ww[2]);
            s[2] = make_float4(cc[3], ww[3], cc[4], ww[4]);
        }

        // uniform loop over compacted members; wave-uniform LDS reads = broadcast
#pragma unroll 2
        for (int i = 0; i < nm; ++i) {
            const float4 q0 = *(const float4*)&pool[wid][i][0];
            const float4 q1 = *(const float4*)&pool[wid][i][4];
            const float4 q2 = *(const float4*)&pool[wid][i][8];
            const float dx = prf - q0.x;
            const float dy = pcf - q0.y;
            const float d2 = fmaf(dx, dx, dy * dy);
            acc = fmaf(q0.w, fexp2(q0.z * d2), acc);
            acc = fmaf(q1.y, fexp2(q1.x * d2), acc);
            acc = fmaf(q1.w, fexp2(q1.z * d2), acc);
            acc = fmaf(q2.y, fexp2(q2.x * d2), acc);
            acc = fmaf(q2.w, fexp2(q2.z * d2), acc);
        }
    }

    // cross-wave reduction: same 64 pixels in every wave
    smred[wid][lane] = acc;
    __syncthreads();
    if (wid == 0) {
        float val = 0.0f;
#pragma unroll
        for (int w = 0; w < NW; ++w) val += smred[w][lane];
        const int r = tr + (lane >> 3);
        const int c = tc + (lane & 7);
        out[((size_t)b << 14) + r * SIDELEN + c] = val;
    }
}

extern "C" void kernel_launch(void* const* d_in, const int* in_sizes, int n_in,
                              void* d_out, int out_size, void* d_ws, size_t ws_size,
                              hipStream_t stream) {
    const float* coords = (const float*)d_in[0];   // (B, A, 3)
    const float* ffa    = (const float*)d_in[1];   // (A, K)
    const float* ffb    = (const float*)d_in[2];   // (A, K)
    float* out = (float*)d_out;

    const int A = in_sizes[1] / KCOEF;
    const int B = in_sizes[0] / (3 * A);

    const int nblk = B * 256;                      // one block per 8x8 tile
    potential_gather_lds<<<dim3(nblk), dim3(TPB), 0, stream>>>(
        coords, ffa, ffb, out, B, A);
}